// Round 1
// baseline (539.799 us; speedup 1.0000x reference)
//
#include <hip/hip_runtime.h>

// QKNorm MHA: B=2, L=2048, D=2048, H=16, hd=128.
// All GEMMs in bf16 MFMA (16x16x32), f32 accumulate.
// Scores bounded by 1/sqrt(128) => softmax without max-subtraction is safe,
// single-pass num/den accumulation (no online rescale).

#define DM   2048
#define HD   128
#define NH   16
#define LSEQ 2048
#define NB   2
#define MTOK 4096  // NB*LSEQ

typedef __bf16 bf16x8 __attribute__((ext_vector_type(8)));
typedef float  f32x4  __attribute__((ext_vector_type(4)));

__device__ __forceinline__ unsigned short f2bf(float f) {
  unsigned u = __builtin_bit_cast(unsigned, f);
  u += 0x7fffu + ((u >> 16) & 1u);
  return (unsigned short)(u >> 16);
}
__device__ __forceinline__ float bf2f(unsigned short h) {
  unsigned u = ((unsigned)h) << 16;
  return __builtin_bit_cast(float, u);
}
__device__ __forceinline__ void gload16(const unsigned short* gc, unsigned short* l) {
  unsigned short* g = const_cast<unsigned short*>(gc);
  __builtin_amdgcn_global_load_lds((__attribute__((address_space(1))) void*)g,
                                   (__attribute__((address_space(3))) void*)l, 16, 0, 0);
}
__device__ __forceinline__ bf16x8 ld_frag_lds(const unsigned short* p) {
  return __builtin_bit_cast(bf16x8, *(const uint4*)p);
}

// ---------------- f32 -> bf16 convert (8 elems/thread) ----------------
__global__ void cvt_bf16_k(const float* __restrict__ s, unsigned short* __restrict__ d, int n8) {
  int i = blockIdx.x * blockDim.x + threadIdx.x;
  if (i >= n8) return;
  const float4* s4 = (const float4*)s;
  float4 a = s4[2 * i], b = s4[2 * i + 1];
  uint4 o;
  o.x = (unsigned)f2bf(a.x) | ((unsigned)f2bf(a.y) << 16);
  o.y = (unsigned)f2bf(a.z) | ((unsigned)f2bf(a.w) << 16);
  o.z = (unsigned)f2bf(b.x) | ((unsigned)f2bf(b.y) << 16);
  o.w = (unsigned)f2bf(b.z) | ((unsigned)f2bf(b.w) << 16);
  ((uint4*)d)[i] = o;
}

// ---------------- GEMM: C[M,N] = A[M,K] * B[N,K]^T + bias ----------------
// 128x128 tile, BK=32, 4 waves (2x2 of 64x64), global_load_lds staging.
template <int OUT_BF16>
__global__ __launch_bounds__(256) void gemm_bt(
    const unsigned short* __restrict__ A, const unsigned short* __restrict__ Bm,
    const float* __restrict__ bias, void* __restrict__ Cv, int M, int N, int K) {
  __shared__ unsigned short As[128 * 32];
  __shared__ unsigned short Bs[128 * 32];
  const int tid = threadIdx.x, wave = tid >> 6, lane = tid & 63;
  const int l15 = lane & 15, l4 = lane >> 4;
  const int wm = wave >> 1, wn = wave & 1;
  const size_t ra0 = (size_t)blockIdx.y * 128;
  const size_t rb0 = (size_t)blockIdx.x * 128;
  f32x4 acc[4][4] = {};
  for (int k0 = 0; k0 < K; k0 += 32) {
    __syncthreads();  // protect LDS vs prev-iter readers
#pragma unroll
    for (int i = 0; i < 2; i++) {
      int s = i * 256 + tid;
      int r = s >> 2, c8 = (s & 3) * 8;
      gload16(A + (ra0 + r) * (size_t)K + k0 + c8, &As[(i * 256 + wave * 64) * 8]);
      gload16(Bm + (rb0 + r) * (size_t)K + k0 + c8, &Bs[(i * 256 + wave * 64) * 8]);
    }
    __syncthreads();  // staging complete (vmcnt drained by barrier)
    bf16x8 af[4], bf[4];
#pragma unroll
    for (int mi = 0; mi < 4; mi++) af[mi] = ld_frag_lds(&As[(wm * 64 + mi * 16 + l15) * 32 + l4 * 8]);
#pragma unroll
    for (int ni = 0; ni < 4; ni++) bf[ni] = ld_frag_lds(&Bs[(wn * 64 + ni * 16 + l15) * 32 + l4 * 8]);
#pragma unroll
    for (int mi = 0; mi < 4; mi++)
#pragma unroll
      for (int ni = 0; ni < 4; ni++)
        acc[mi][ni] = __builtin_amdgcn_mfma_f32_16x16x32_bf16(af[mi], bf[ni], acc[mi][ni], 0, 0, 0);
  }
  const int col0 = blockIdx.x * 128 + wn * 64;
  const int row0 = blockIdx.y * 128 + wm * 64;
#pragma unroll
  for (int ni = 0; ni < 4; ni++) {
    int col = col0 + ni * 16 + l15;
    float bv = bias[col];
#pragma unroll
    for (int mi = 0; mi < 4; mi++) {
      int row = row0 + mi * 16 + l4 * 4;
#pragma unroll
      for (int r = 0; r < 4; r++) {
        float v = acc[mi][ni][r] + bv;
        if (OUT_BF16)
          ((unsigned short*)Cv)[(size_t)(row + r) * N + col] = f2bf(v);
        else
          ((float*)Cv)[(size_t)(row + r) * N + col] = v;
      }
    }
  }
}

// ---------------- in-place L2 normalize rows of 128 bf16 ----------------
__global__ void qknorm_k(unsigned short* __restrict__ q) {
  int row = blockIdx.x * 4 + (threadIdx.x >> 6);  // (token*NH + head)
  int lane = threadIdx.x & 63;
  unsigned* p = (unsigned*)(q + (size_t)row * HD);
  unsigned w = p[lane];
  float a = bf2f((unsigned short)(w & 0xffff));
  float b = bf2f((unsigned short)(w >> 16));
  float ss = a * a + b * b;
#pragma unroll
  for (int m = 1; m < 64; m <<= 1) ss += __shfl_xor(ss, m);
  float inv = 1.0f / (sqrtf(ss) + 1e-6f);
  p[lane] = (unsigned)f2bf(a * inv) | ((unsigned)f2bf(b * inv) << 16);
}

// ---------------- V transpose: Vt[bh][d][l] = V[b,l,h*HD+d] ----------------
__global__ void vtrans_k(const unsigned short* __restrict__ V, unsigned short* __restrict__ Vt) {
  __shared__ unsigned short t[128 * 136];
  const int bh = blockIdx.y, b = bh >> 4, h = bh & 15;
  const int l0 = blockIdx.x * 128;
  const int tid = threadIdx.x;
#pragma unroll
  for (int i = 0; i < 8; i++) {
    int s = i * 256 + tid;
    int r = s >> 4, c8 = (s & 15) * 8;
    uint4 v = *(const uint4*)(V + ((size_t)(b * LSEQ + l0 + r)) * DM + h * HD + c8);
    *(uint4*)&t[r * 136 + c8] = v;
  }
  __syncthreads();
#pragma unroll
  for (int i = 0; i < 8; i++) {
    int s = i * 256 + tid;
    int dd = s >> 4, l8 = (s & 15) * 8;
    unsigned short tmp[8];
#pragma unroll
    for (int j = 0; j < 8; j++) tmp[j] = t[(l8 + j) * 136 + dd];
    *(uint4*)(Vt + ((size_t)bh * HD + dd) * LSEQ + l0 + l8) = *(const uint4*)tmp;
  }
}

// ---------------- attention ----------------
// grid: (L/64, B*H). 4 waves; wave owns 16 q-rows. KV tile = 64.
// num/den accumulation, no max subtraction (|s| <= 1/sqrt(hd)).
__global__ __launch_bounds__(256) void attn_k(
    const unsigned short* __restrict__ Q, const unsigned short* __restrict__ Kn,
    const unsigned short* __restrict__ Vt, unsigned short* __restrict__ Oa) {
  __shared__ unsigned short Ks[64 * 136];   // [kv][d] pad 136
  __shared__ unsigned short Vs[128 * 72];   // [d][kv] pad 72
  __shared__ unsigned short Ps[4][16 * 72]; // per-wave P, pad 72
  const int bh = blockIdx.y, b = bh >> 4, h = bh & 15;
  const int q0 = blockIdx.x * 64;
  const int tid = threadIdx.x, wave = tid >> 6, lane = tid & 63;
  const int l15 = lane & 15, l4 = lane >> 4;
  const float scale = 0.08838834764831845f;  // 1/sqrt(128)

  bf16x8 qf[4];
  {
    const unsigned short* qp = Q + ((size_t)(b * LSEQ + q0 + wave * 16 + l15)) * DM + h * HD + l4 * 8;
#pragma unroll
    for (int kk = 0; kk < 4; kk++) qf[kk] = ld_frag_lds(qp + kk * 32);
  }
  f32x4 oacc[8] = {};
  float den[4] = {0.f, 0.f, 0.f, 0.f};

  for (int kv0 = 0; kv0 < LSEQ; kv0 += 64) {
    __syncthreads();
#pragma unroll
    for (int i = 0; i < 4; i++) {  // stage K tile 64x128
      int s = i * 256 + tid;
      int r = s >> 4, c8 = (s & 15) * 8;
      uint4 v = *(const uint4*)(Kn + ((size_t)(b * LSEQ + kv0 + r)) * DM + h * HD + c8);
      *(uint4*)&Ks[r * 136 + c8] = v;
    }
#pragma unroll
    for (int i = 0; i < 4; i++) {  // stage Vt tile 128x64
      int s = i * 256 + tid;
      int dd = s >> 3, c8 = (s & 7) * 8;
      uint4 v = *(const uint4*)(Vt + ((size_t)bh * HD + dd) * LSEQ + kv0 + c8);
      *(uint4*)&Vs[dd * 72 + c8] = v;
    }
    __syncthreads();
    // S = Q K^T  (16 q-rows x 64 kv-cols per wave)
#pragma unroll
    for (int ni = 0; ni < 4; ni++) {
      f32x4 sacc = {0.f, 0.f, 0.f, 0.f};
#pragma unroll
      for (int kk = 0; kk < 4; kk++) {
        bf16x8 kf = ld_frag_lds(&Ks[(ni * 16 + l15) * 136 + kk * 32 + l4 * 8]);
        sacc = __builtin_amdgcn_mfma_f32_16x16x32_bf16(qf[kk], kf, sacc, 0, 0, 0);
      }
#pragma unroll
      for (int r = 0; r < 4; r++) {
        float p = __expf(sacc[r] * scale);
        den[r] += p;
        Ps[wave][(l4 * 4 + r) * 72 + ni * 16 + l15] = f2bf(p);
      }
    }
    // PV: out += P[16,64] * V[64,128]
#pragma unroll
    for (int ks = 0; ks < 2; ks++) {
      bf16x8 pf = ld_frag_lds(&Ps[wave][l15 * 72 + ks * 32 + l4 * 8]);
#pragma unroll
      for (int d0 = 0; d0 < 8; d0++) {
        bf16x8 vf = ld_frag_lds(&Vs[(d0 * 16 + l15) * 72 + ks * 32 + l4 * 8]);
        oacc[d0] = __builtin_amdgcn_mfma_f32_16x16x32_bf16(pf, vf, oacc[d0], 0, 0, 0);
      }
    }
  }
  // reduce den across the 16 lanes sharing each row
#pragma unroll
  for (int r = 0; r < 4; r++) {
    float s = den[r];
    s += __shfl_xor(s, 1);
    s += __shfl_xor(s, 2);
    s += __shfl_xor(s, 4);
    s += __shfl_xor(s, 8);
    den[r] = s;
  }
#pragma unroll
  for (int d0 = 0; d0 < 8; d0++) {
#pragma unroll
    for (int r = 0; r < 4; r++) {
      float v = oacc[d0][r] / den[r];
      Oa[((size_t)(b * LSEQ + q0 + wave * 16 + l4 * 4 + r)) * DM + h * HD + d0 * 16 + l15] = f2bf(v);
    }
  }
}

extern "C" void kernel_launch(void* const* d_in, const int* in_sizes, int n_in,
                              void* d_out, int out_size, void* d_ws, size_t ws_size,
                              hipStream_t stream) {
  const float* x  = (const float*)d_in[0];
  const float* Wq = (const float*)d_in[1];
  const float* bq = (const float*)d_in[2];
  const float* Wk = (const float*)d_in[3];
  const float* bk = (const float*)d_in[4];
  const float* Wv = (const float*)d_in[5];
  const float* bv = (const float*)d_in[6];
  const float* Wo = (const float*)d_in[7];
  const float* bo = (const float*)d_in[8];

  char* ws = (char*)d_ws;
  unsigned short* xb  = (unsigned short*)(ws + 0);           // 16 MiB (reused as attn-out)
  unsigned short* wqb = (unsigned short*)(ws + 16777216);    // 8 MiB
  unsigned short* wkb = (unsigned short*)(ws + 25165824);
  unsigned short* wvb = (unsigned short*)(ws + 33554432);
  unsigned short* wob = (unsigned short*)(ws + 41943040);
  unsigned short* qb  = (unsigned short*)(ws + 50331648);    // 16 MiB
  unsigned short* kb  = (unsigned short*)(ws + 67108864);
  unsigned short* vb  = (unsigned short*)(ws + 83886080);
  unsigned short* vt  = (unsigned short*)(ws + 100663296);   // 16 MiB, end 117440512
  unsigned short* ao  = xb;  // alias: x no longer needed once attention runs

  // 1. casts
  cvt_bf16_k<<<4096, 256, 0, stream>>>(x, xb, MTOK * DM / 8);
  cvt_bf16_k<<<2048, 256, 0, stream>>>(Wq, wqb, DM * DM / 8);
  cvt_bf16_k<<<2048, 256, 0, stream>>>(Wk, wkb, DM * DM / 8);
  cvt_bf16_k<<<2048, 256, 0, stream>>>(Wv, wvb, DM * DM / 8);
  cvt_bf16_k<<<2048, 256, 0, stream>>>(Wo, wob, DM * DM / 8);

  // 2. projections
  dim3 gg(DM / 128, MTOK / 128);
  gemm_bt<1><<<gg, 256, 0, stream>>>(xb, wqb, bq, qb, MTOK, DM, DM);
  gemm_bt<1><<<gg, 256, 0, stream>>>(xb, wkb, bk, kb, MTOK, DM, DM);
  gemm_bt<1><<<gg, 256, 0, stream>>>(xb, wvb, bv, vb, MTOK, DM, DM);

  // 3. qk norm (in place)
  qknorm_k<<<MTOK * NH / 4, 256, 0, stream>>>(qb);
  qknorm_k<<<MTOK * NH / 4, 256, 0, stream>>>(kb);

  // 4. V transpose per head
  vtrans_k<<<dim3(LSEQ / 128, NB * NH), 256, 0, stream>>>(vb, vt);

  // 5. attention
  attn_k<<<dim3(LSEQ / 64, NB * NH), 256, 0, stream>>>(qb, kb, vt, ao);

  // 6. output projection (f32 out)
  gemm_bt<0><<<gg, 256, 0, stream>>>(ao, wob, bo, (float*)d_out, MTOK, DM, DM);
}

// Round 2
// 440.830 us; speedup vs baseline: 1.2245x; 1.2245x over previous
//
#include <hip/hip_runtime.h>

// QKNorm MHA: B=2, L=2048, D=2048, H=16, hd=128.
// Round 2: rebuilt attention — 4 waves x 32 q-rows, XOR-swizzled linear LDS
// (K/V/P), reg-prefetch staging (T14), XCD-chunked block swizzle (T1),
// Q-norm folded into attn.

#define DM   2048
#define HD   128
#define NH   16
#define LSEQ 2048
#define NB   2
#define MTOK 4096  // NB*LSEQ

typedef __bf16 bf16x8 __attribute__((ext_vector_type(8)));
typedef float  f32x4  __attribute__((ext_vector_type(4)));

__device__ __forceinline__ unsigned short f2bf(float f) {
  unsigned u = __builtin_bit_cast(unsigned, f);
  u += 0x7fffu + ((u >> 16) & 1u);
  return (unsigned short)(u >> 16);
}
__device__ __forceinline__ float bf2f(unsigned short h) {
  unsigned u = ((unsigned)h) << 16;
  return __builtin_bit_cast(float, u);
}
__device__ __forceinline__ void gload16(const unsigned short* gc, unsigned short* l) {
  unsigned short* g = const_cast<unsigned short*>(gc);
  __builtin_amdgcn_global_load_lds((__attribute__((address_space(1))) void*)g,
                                   (__attribute__((address_space(3))) void*)l, 16, 0, 0);
}
__device__ __forceinline__ bf16x8 ld_frag(const void* p) {
  return __builtin_bit_cast(bf16x8, *(const uint4*)p);
}

// ---------------- f32 -> bf16 convert (8 elems/thread) ----------------
__global__ void cvt_bf16_k(const float* __restrict__ s, unsigned short* __restrict__ d, int n8) {
  int i = blockIdx.x * blockDim.x + threadIdx.x;
  if (i >= n8) return;
  const float4* s4 = (const float4*)s;
  float4 a = s4[2 * i], b = s4[2 * i + 1];
  uint4 o;
  o.x = (unsigned)f2bf(a.x) | ((unsigned)f2bf(a.y) << 16);
  o.y = (unsigned)f2bf(a.z) | ((unsigned)f2bf(a.w) << 16);
  o.z = (unsigned)f2bf(b.x) | ((unsigned)f2bf(b.y) << 16);
  o.w = (unsigned)f2bf(b.z) | ((unsigned)f2bf(b.w) << 16);
  ((uint4*)d)[i] = o;
}

// ---------------- GEMM: C[M,N] = A[M,K] * B[N,K]^T + bias ----------------
template <int OUT_BF16>
__global__ __launch_bounds__(256) void gemm_bt(
    const unsigned short* __restrict__ A, const unsigned short* __restrict__ Bm,
    const float* __restrict__ bias, void* __restrict__ Cv, int M, int N, int K) {
  __shared__ unsigned short As[128 * 32];
  __shared__ unsigned short Bs[128 * 32];
  const int tid = threadIdx.x, wave = tid >> 6, lane = tid & 63;
  const int l15 = lane & 15, l4 = lane >> 4;
  const int wm = wave >> 1, wn = wave & 1;
  const size_t ra0 = (size_t)blockIdx.y * 128;
  const size_t rb0 = (size_t)blockIdx.x * 128;
  f32x4 acc[4][4] = {};
  for (int k0 = 0; k0 < K; k0 += 32) {
    __syncthreads();
#pragma unroll
    for (int i = 0; i < 2; i++) {
      int s = i * 256 + tid;
      int r = s >> 2, c8 = (s & 3) * 8;
      gload16(A + (ra0 + r) * (size_t)K + k0 + c8, &As[(i * 256 + wave * 64) * 8]);
      gload16(Bm + (rb0 + r) * (size_t)K + k0 + c8, &Bs[(i * 256 + wave * 64) * 8]);
    }
    __syncthreads();
    bf16x8 af[4], bfr[4];
#pragma unroll
    for (int mi = 0; mi < 4; mi++) af[mi] = ld_frag(&As[(wm * 64 + mi * 16 + l15) * 32 + l4 * 8]);
#pragma unroll
    for (int ni = 0; ni < 4; ni++) bfr[ni] = ld_frag(&Bs[(wn * 64 + ni * 16 + l15) * 32 + l4 * 8]);
#pragma unroll
    for (int mi = 0; mi < 4; mi++)
#pragma unroll
      for (int ni = 0; ni < 4; ni++)
        acc[mi][ni] = __builtin_amdgcn_mfma_f32_16x16x32_bf16(af[mi], bfr[ni], acc[mi][ni], 0, 0, 0);
  }
  const int col0 = blockIdx.x * 128 + wn * 64;
  const int row0 = blockIdx.y * 128 + wm * 64;
#pragma unroll
  for (int ni = 0; ni < 4; ni++) {
    int col = col0 + ni * 16 + l15;
    float bv = bias[col];
#pragma unroll
    for (int mi = 0; mi < 4; mi++) {
      int row = row0 + mi * 16 + l4 * 4;
#pragma unroll
      for (int r = 0; r < 4; r++) {
        float v = acc[mi][ni][r] + bv;
        if (OUT_BF16)
          ((unsigned short*)Cv)[(size_t)(row + r) * N + col] = f2bf(v);
        else
          ((float*)Cv)[(size_t)(row + r) * N + col] = v;
      }
    }
  }
}

// ---------------- in-place L2 normalize rows of 128 bf16 (K only now) ----
__global__ void qknorm_k(unsigned short* __restrict__ q) {
  int row = blockIdx.x * 4 + (threadIdx.x >> 6);
  int lane = threadIdx.x & 63;
  unsigned* p = (unsigned*)(q + (size_t)row * HD);
  unsigned w = p[lane];
  float a = bf2f((unsigned short)(w & 0xffff));
  float b = bf2f((unsigned short)(w >> 16));
  float ss = a * a + b * b;
#pragma unroll
  for (int m = 1; m < 64; m <<= 1) ss += __shfl_xor(ss, m);
  float inv = 1.0f / (sqrtf(ss) + 1e-6f);
  p[lane] = (unsigned)f2bf(a * inv) | ((unsigned)f2bf(b * inv) << 16);
}

// ---------------- V transpose: Vt[bh][d][l] = V[b,l,h*HD+d] ----------------
__global__ void vtrans_k(const unsigned short* __restrict__ V, unsigned short* __restrict__ Vt) {
  __shared__ unsigned short t[128 * 136];
  const int bh = blockIdx.y, b = bh >> 4, h = bh & 15;
  const int l0 = blockIdx.x * 128;
  const int tid = threadIdx.x;
#pragma unroll
  for (int i = 0; i < 8; i++) {
    int s = i * 256 + tid;
    int r = s >> 4, c8 = (s & 15) * 8;
    uint4 v = *(const uint4*)(V + ((size_t)(b * LSEQ + l0 + r)) * DM + h * HD + c8);
    *(uint4*)&t[r * 136 + c8] = v;
  }
  __syncthreads();
#pragma unroll
  for (int i = 0; i < 8; i++) {
    int s = i * 256 + tid;
    int dd = s >> 4, l8 = (s & 15) * 8;
    unsigned short tmp[8];
#pragma unroll
    for (int j = 0; j < 8; j++) tmp[j] = t[(l8 + j) * 136 + dd];
    *(uint4*)(Vt + ((size_t)bh * HD + dd) * LSEQ + l0 + l8) = *(const uint4*)tmp;
  }
}

// ---------------- attention ----------------
// grid flat 512 = (L/128=16) x (B*H=32), XCD-chunked swizzle.
// 4 waves x 32 q-rows. KV tile = 64. Q-norm fused. XOR-swizzled LDS.
__global__ __launch_bounds__(256) void attn_k(
    const unsigned short* __restrict__ Q, const unsigned short* __restrict__ Kn,
    const unsigned short* __restrict__ Vt, unsigned short* __restrict__ Oa) {
  __shared__ unsigned short Ks[64 * 128];   // [kv][d], 16B chunks XOR row&7
  __shared__ unsigned short Vs[128 * 64];   // [d][kv], XOR row&7
  __shared__ unsigned short Ps[4][32 * 64]; // per-wave [q][kv], XOR row&7

  // XCD-chunked bijective swizzle (512 wgs, 8 XCDs, 64/XCD => heads grouped)
  int flat = blockIdx.x + blockIdx.y * 16;
  int wg = (flat & 7) * 64 + (flat >> 3);
  const int qb = wg & 15, bh = wg >> 4;
  const int b = bh >> 4, h = bh & 15;
  const int q0 = qb * 128;
  const int tid = threadIdx.x, wave = tid >> 6, lane = tid & 63;
  const int l15 = lane & 15, l4 = lane >> 4;
  const int lx = l15 & 7;  // row&7 for all frag-read rows (row = *16 + l15)
  const float scale = 0.08838834764831845f;  // 1/sqrt(128)

  // ---- load Q (32 rows/wave) + fused L2 norm ----
  bf16x8 qf[2][4];
  {
#pragma unroll
    for (int rg = 0; rg < 2; rg++) {
      const unsigned short* qp =
          Q + ((size_t)(b * LSEQ + q0 + wave * 32 + rg * 16 + l15)) * DM + h * HD + l4 * 8;
      uint4 qv[4];
      float qs[4][8];
      float ss = 0.f;
#pragma unroll
      for (int kk = 0; kk < 4; kk++) qv[kk] = *(const uint4*)(qp + kk * 32);
#pragma unroll
      for (int kk = 0; kk < 4; kk++) {
        const unsigned* w = (const unsigned*)&qv[kk];
#pragma unroll
        for (int m = 0; m < 4; m++) {
          float a = bf2f((unsigned short)(w[m] & 0xffff));
          float c = bf2f((unsigned short)(w[m] >> 16));
          qs[kk][2 * m] = a; qs[kk][2 * m + 1] = c;
          ss += a * a + c * c;
        }
      }
      ss += __shfl_xor(ss, 16);
      ss += __shfl_xor(ss, 32);
      float inv = 1.0f / (sqrtf(ss) + 1e-6f);
      uint4 qo;
      unsigned* wo = (unsigned*)&qo;
#pragma unroll
      for (int kk = 0; kk < 4; kk++) {
#pragma unroll
        for (int m = 0; m < 4; m++)
          wo[m] = (unsigned)f2bf(qs[kk][2 * m] * inv) |
                  ((unsigned)f2bf(qs[kk][2 * m + 1] * inv) << 16);
        qf[rg][kk] = __builtin_bit_cast(bf16x8, qo);
      }
    }
  }

  f32x4 oacc[2][8] = {};
  float den[2][4] = {};
  uint4 pk[4], pv[4];

  const unsigned short* Kbase = Kn + ((size_t)(b * LSEQ)) * DM + h * HD;
  const unsigned short* Vbase = Vt + ((size_t)bh * HD) * LSEQ;

  // prologue: issue loads for tile 0
#pragma unroll
  for (int i = 0; i < 4; i++) {
    int s = i * 256 + tid;
    pk[i] = *(const uint4*)(Kbase + ((size_t)(s >> 4)) * DM + (s & 15) * 8);
    pv[i] = *(const uint4*)(Vbase + ((size_t)(s >> 3)) * LSEQ + (s & 7) * 8);
  }

  for (int kv0 = 0; kv0 < LSEQ; kv0 += 64) {
    __syncthreads();  // prev-tile readers done
    // ds_write staged regs (compiler inserts vmcnt wait)
#pragma unroll
    for (int i = 0; i < 4; i++) {
      int s = i * 256 + tid;
      int kr = s >> 4, kc = s & 15;
      *(uint4*)((char*)Ks + kr * 256 + ((kc ^ (kr & 7)) << 4)) = pk[i];
      int vr = s >> 3, vc = s & 7;
      *(uint4*)((char*)Vs + vr * 128 + ((vc ^ (vr & 7)) << 4)) = pv[i];
    }
    __syncthreads();
    // prefetch next tile into regs (overlaps with compute below)
    if (kv0 + 64 < LSEQ) {
#pragma unroll
      for (int i = 0; i < 4; i++) {
        int s = i * 256 + tid;
        pk[i] = *(const uint4*)(Kbase + ((size_t)(kv0 + 64 + (s >> 4))) * DM + (s & 15) * 8);
        pv[i] = *(const uint4*)(Vbase + ((size_t)(s >> 3)) * LSEQ + kv0 + 64 + (s & 7) * 8);
      }
    }

    // ---- QK^T + exp + P store ----
#pragma unroll
    for (int ni = 0; ni < 4; ni++) {
      f32x4 s0 = {0.f, 0.f, 0.f, 0.f}, s1 = {0.f, 0.f, 0.f, 0.f};
#pragma unroll
      for (int kk = 0; kk < 4; kk++) {
        bf16x8 kf = ld_frag((char*)Ks + (ni * 16 + l15) * 256 + (((kk * 4 + l4) ^ lx) << 4));
        s0 = __builtin_amdgcn_mfma_f32_16x16x32_bf16(qf[0][kk], kf, s0, 0, 0, 0);
        s1 = __builtin_amdgcn_mfma_f32_16x16x32_bf16(qf[1][kk], kf, s1, 0, 0, 0);
      }
      char* pbase = (char*)&Ps[wave][0];
      int colb = ((ni * 2 + (l15 >> 3)) << 4) + (l15 & 7) * 2;  // chunk + within-chunk
#pragma unroll
      for (int r = 0; r < 4; r++) {
        int row = l4 * 4 + r;
        int cs = (((row & 7) << 4));  // XOR applied on chunk bits of colb
        float p0 = __expf(s0[r] * scale);
        float p1 = __expf(s1[r] * scale);
        den[0][r] += p0;
        den[1][r] += p1;
        *(unsigned short*)(pbase + row * 128 + (colb ^ cs)) = f2bf(p0);
        *(unsigned short*)(pbase + (16 + row) * 128 + (colb ^ cs)) = f2bf(p1);
      }
    }
    // ---- PV ----
#pragma unroll
    for (int ks = 0; ks < 2; ks++) {
      int cx = ((ks * 4 + l4) ^ lx) << 4;
      bf16x8 pf0 = ld_frag((char*)&Ps[wave][0] + l15 * 128 + cx);
      bf16x8 pf1 = ld_frag((char*)&Ps[wave][0] + (16 + l15) * 128 + cx);
#pragma unroll
      for (int d0 = 0; d0 < 8; d0++) {
        bf16x8 vf = ld_frag((char*)Vs + (d0 * 16 + l15) * 128 + cx);
        oacc[0][d0] = __builtin_amdgcn_mfma_f32_16x16x32_bf16(pf0, vf, oacc[0][d0], 0, 0, 0);
        oacc[1][d0] = __builtin_amdgcn_mfma_f32_16x16x32_bf16(pf1, vf, oacc[1][d0], 0, 0, 0);
      }
    }
  }

  // den: reduce across the 16 lanes (l15) sharing each row
#pragma unroll
  for (int rg = 0; rg < 2; rg++)
#pragma unroll
    for (int r = 0; r < 4; r++) {
      float s = den[rg][r];
      s += __shfl_xor(s, 1);
      s += __shfl_xor(s, 2);
      s += __shfl_xor(s, 4);
      s += __shfl_xor(s, 8);
      den[rg][r] = s;
    }
#pragma unroll
  for (int rg = 0; rg < 2; rg++)
#pragma unroll
    for (int d0 = 0; d0 < 8; d0++)
#pragma unroll
      for (int r = 0; r < 4; r++) {
        float v = oacc[rg][d0][r] / den[rg][r];
        Oa[((size_t)(b * LSEQ + q0 + wave * 32 + rg * 16 + l4 * 4 + r)) * DM + h * HD +
           d0 * 16 + l15] = f2bf(v);
      }
}

extern "C" void kernel_launch(void* const* d_in, const int* in_sizes, int n_in,
                              void* d_out, int out_size, void* d_ws, size_t ws_size,
                              hipStream_t stream) {
  const float* x  = (const float*)d_in[0];
  const float* Wq = (const float*)d_in[1];
  const float* bq = (const float*)d_in[2];
  const float* Wk = (const float*)d_in[3];
  const float* bk = (const float*)d_in[4];
  const float* Wv = (const float*)d_in[5];
  const float* bv = (const float*)d_in[6];
  const float* Wo = (const float*)d_in[7];
  const float* bo = (const float*)d_in[8];

  char* ws = (char*)d_ws;
  unsigned short* xb  = (unsigned short*)(ws + 0);           // 16 MiB (reused as attn-out)
  unsigned short* wqb = (unsigned short*)(ws + 16777216);    // 8 MiB
  unsigned short* wkb = (unsigned short*)(ws + 25165824);
  unsigned short* wvb = (unsigned short*)(ws + 33554432);
  unsigned short* wob = (unsigned short*)(ws + 41943040);
  unsigned short* qb  = (unsigned short*)(ws + 50331648);    // 16 MiB
  unsigned short* kb  = (unsigned short*)(ws + 67108864);
  unsigned short* vb  = (unsigned short*)(ws + 83886080);
  unsigned short* vt  = (unsigned short*)(ws + 100663296);   // 16 MiB, end 117440512
  unsigned short* ao  = xb;

  cvt_bf16_k<<<4096, 256, 0, stream>>>(x, xb, MTOK * DM / 8);
  cvt_bf16_k<<<2048, 256, 0, stream>>>(Wq, wqb, DM * DM / 8);
  cvt_bf16_k<<<2048, 256, 0, stream>>>(Wk, wkb, DM * DM / 8);
  cvt_bf16_k<<<2048, 256, 0, stream>>>(Wv, wvb, DM * DM / 8);
  cvt_bf16_k<<<2048, 256, 0, stream>>>(Wo, wob, DM * DM / 8);

  dim3 gg(DM / 128, MTOK / 128);
  gemm_bt<1><<<gg, 256, 0, stream>>>(xb, wqb, bq, qb, MTOK, DM, DM);
  gemm_bt<1><<<gg, 256, 0, stream>>>(xb, wkb, bk, kb, MTOK, DM, DM);
  gemm_bt<1><<<gg, 256, 0, stream>>>(xb, wvb, bv, vb, MTOK, DM, DM);

  qknorm_k<<<MTOK * NH / 4, 256, 0, stream>>>(kb);  // K only; Q-norm fused in attn

  vtrans_k<<<dim3(LSEQ / 128, NB * NH), 256, 0, stream>>>(vb, vt);

  attn_k<<<dim3(LSEQ / 128, NB * NH), 256, 0, stream>>>(qb, kb, vt, ao);

  gemm_bt<0><<<gg, 256, 0, stream>>>(ao, wob, bo, (float*)d_out, MTOK, DM, DM);
}